// Round 1
// baseline (178.889 us; speedup 1.0000x reference)
//
#include <hip/hip_runtime.h>
#include <hip/hip_bf16.h>
#include <math.h>

// Problem constants
#define TT 2048
#define BB 2
#define DM 1024
#define NH 16
#define HD 64
#define KVD 16
#define BT (BB*TT)   // 4096 rows total
#define QP 256       // NH*KVD

typedef short short8  __attribute__((ext_vector_type(8)));
typedef short short4v __attribute__((ext_vector_type(4)));
typedef float f32x4   __attribute__((ext_vector_type(4)));

static __device__ __forceinline__ short f2bf(float f) {
    union { float f; unsigned u; } v; v.f = f;
    unsigned r = v.u + 0x7fffu + ((v.u >> 16) & 1u);   // round-to-nearest-even
    return (short)(r >> 16);
}

// ---------------- prep 1: absorbed weights ----------------
// Wqt[c][d]  = bf16( log2e/8 * sum_e Wq[d][h*64+e]*Wk[j][h*64+e] ),  c = h*16+j
// Wvot[n][c] = bf16( sum_e Wv[j][h*64+e]*Wo[h*64+e][n] )
// bqp[c]     = log2e/8 * sum_e bq[h*64+e]*Wk[j][h*64+e]
// bop[n]     = bo[n] + sum_d bv[d]*Wo[d][n]
__global__ __launch_bounds__(256) void prep_w(
    const float* __restrict__ Wk, const float* __restrict__ Wv,
    const float* __restrict__ Wq, const float* __restrict__ bq,
    const float* __restrict__ Wo, const float* __restrict__ bv,
    const float* __restrict__ bo,
    short* __restrict__ Wqt, short* __restrict__ Wvot,
    float* __restrict__ bqp, float* __restrict__ bop)
{
    const float SC = 0.18033688011112042f;  // log2(e)/8
    int bid = blockIdx.x, tid = threadIdx.x;
    if (bid < 256) {                       // Wqt, one block per c
        int c = bid, h = c >> 4, j = c & 15;
        __shared__ float wk[64];
        if (tid < 64) wk[tid] = Wk[j*DM + h*HD + tid];
        __syncthreads();
        for (int i = 0; i < 4; ++i) {
            int d = i*256 + tid;
            const float4* wq4 = (const float4*)(Wq + d*DM + h*HD);
            const float4* wk4 = (const float4*)wk;
            float acc = 0.f;
            #pragma unroll
            for (int e4 = 0; e4 < 16; ++e4) {
                float4 a4 = wq4[e4], b4 = wk4[e4];
                acc += a4.x*b4.x + a4.y*b4.y + a4.z*b4.z + a4.w*b4.w;
            }
            Wqt[c*DM + d] = f2bf(acc * SC);
        }
    } else if (bid < 272) {                // Wvot, one block per h
        int h = bid - 256;
        __shared__ float wv[16][64];
        for (int idx = tid; idx < 1024; idx += 256) {
            int j = idx >> 6, e = idx & 63;
            wv[j][e] = Wv[j*DM + h*HD + e];
        }
        __syncthreads();
        for (int i = 0; i < 4; ++i) {
            int n = i*256 + tid;
            float acc[16];
            #pragma unroll
            for (int j = 0; j < 16; ++j) acc[j] = 0.f;
            for (int e = 0; e < 64; ++e) {
                float wo = Wo[(h*HD + e)*DM + n];
                #pragma unroll
                for (int j = 0; j < 16; ++j) acc[j] += wv[j][e] * wo;
            }
            short8 o0, o1;
            #pragma unroll
            for (int j = 0; j < 8; ++j) { o0[j] = f2bf(acc[j]); o1[j] = f2bf(acc[j+8]); }
            *(short8*)(Wvot + n*QP + h*16)     = o0;
            *(short8*)(Wvot + n*QP + h*16 + 8) = o1;
        }
    } else if (bid == 272) {               // bqp
        int c = tid, h = c >> 4, j = c & 15;
        float acc = 0.f;
        #pragma unroll 8
        for (int e = 0; e < 64; ++e) acc += bq[h*HD+e] * Wk[j*DM + h*HD + e];
        bqp[c] = acc * SC;
    } else {                               // bop, 4 blocks
        int n = (bid - 273)*256 + tid;
        float acc = bo[n];
        #pragma unroll 8
        for (int d = 0; d < DM; ++d) acc += bv[d] * Wo[d*DM + n];
        bop[n] = acc;
    }
}

// ---------------- prep 2: x -> bf16, kvc (latent) ----------------
// kvc32: [BT][32] bf16, latent padded with zeros (QK B-side)
// kvcT : [B][16][T] bf16 (PV B-side)
__global__ __launch_bounds__(256) void prep_x(
    const float* __restrict__ x, const float* __restrict__ Wc,
    const float* __restrict__ bc,
    short* __restrict__ x_bf, short* __restrict__ kvc32, short* __restrict__ kvcT)
{
    int t0 = blockIdx.x * 4, tid = threadIdx.x;
    __shared__ float xs[4][DM];
    __shared__ float part[4][16][17];
    #pragma unroll
    for (int i = 0; i < 4; ++i) {
        float4 xv = *(const float4*)(x + (t0+i)*DM + tid*4);
        *(float4*)(&xs[i][tid*4]) = xv;
        short4v xb;
        xb[0]=f2bf(xv.x); xb[1]=f2bf(xv.y); xb[2]=f2bf(xv.z); xb[3]=f2bf(xv.w);
        *(short4v*)(x_bf + (t0+i)*DM + tid*4) = xb;
    }
    __syncthreads();
    int g = tid >> 4, n = tid & 15;
    float a0=0.f, a1=0.f, a2=0.f, a3=0.f;
    #pragma unroll 4
    for (int k = 0; k < 64; ++k) {
        float wc = Wc[(g*64 + k)*KVD + n];
        a0 += xs[0][g*64+k]*wc; a1 += xs[1][g*64+k]*wc;
        a2 += xs[2][g*64+k]*wc; a3 += xs[3][g*64+k]*wc;
    }
    part[0][g][n]=a0; part[1][g][n]=a1; part[2][g][n]=a2; part[3][g][n]=a3;
    __syncthreads();
    if (tid < 64) {
        int i = tid >> 4, nn = tid & 15;
        float s = bc[nn];
        #pragma unroll
        for (int gg = 0; gg < 16; ++gg) s += part[i][gg][nn];
        short v = f2bf(s);
        int t = t0 + i;
        kvc32[t*32 + nn]      = v;
        kvc32[t*32 + 16 + nn] = 0;
        int b = t >> 11, tl = t & (TT-1);
        kvcT[(b*KVD + nn)*TT + tl] = v;
    }
}

// ---------------- q' GEMM: q32 = (x @ Wq' + bq') * log2e/8, padded to 32/head ----------------
__global__ __launch_bounds__(256) void qgemm(
    const short* __restrict__ x_bf, const short* __restrict__ Wqt,
    const float* __restrict__ bqp, short* __restrict__ q32)
{
    int bid = blockIdx.x;
    int w = threadIdx.x >> 6, lane = threadIdx.x & 63;
    int l15 = lane & 15, g = lane >> 4;
    int m0 = (bid >> 4)*64 + w*16;
    int nb = (bid & 15)*16;
    f32x4 acc = {0.f,0.f,0.f,0.f};
    const short* arow = x_bf + (m0 + l15)*DM + 8*g;
    const short* brow = Wqt  + (nb + l15)*DM + 8*g;
    for (int k0 = 0; k0 < DM; k0 += 32) {
        short8 a = *(const short8*)(arow + k0);
        short8 b = *(const short8*)(brow + k0);
        acc = __builtin_amdgcn_mfma_f32_16x16x32_bf16(a, b, acc, 0, 0, 0);
    }
    int c = nb + l15;
    float bias = bqp[c];
    int co = (c >> 4)*32 + l15;
    #pragma unroll
    for (int r = 0; r < 4; ++r) {
        int row = m0 + 4*g + r;
        q32[row*512 + co]      = f2bf(acc[r] + bias);
        q32[row*512 + co + 16] = 0;
    }
}

// ---------------- causal latent attention ----------------
// Per wave: 16 q rows of one (b,h). S tile via mfma(A=q32, B=kvc32), K=32 (latent 16 + zero pad).
// No max-subtraction (|S*log2e| small): P = exp2(S), denominator accumulated per-lane.
// P -> A-frag via per-wave LDS [16][40] tile; PV: U += P @ kvc (B-frag from kvcT).
__global__ __launch_bounds__(256) void attn(
    const short* __restrict__ q32, const short* __restrict__ kvc32,
    const short* __restrict__ kvcT, short* __restrict__ u_bf)
{
    int bid = blockIdx.x;
    int r5 = bid >> 5;
    int aa = r5 & 7, b2 = r5 >> 3;
    // balance causal triangle across CUs: each CU's 4 blocks get complementary lengths
    int qb = (b2 & 1) ? (31 - 2*aa - (b2 >> 1)) : (2*aa + (b2 >> 1));
    int bh = bid & 31, b = bh >> 4, h = bh & 15;
    int w = threadIdx.x >> 6, lane = threadIdx.x & 63;
    int l15 = lane & 15, g = lane >> 4;
    int qbase = qb*64 + w*16;
    __shared__ short p_lds[4][16][40];   // per-wave P tile, padded rows (80B) for banks
    short (*pl)[40] = p_lds[w];

    short8 qa = *(const short8*)(q32 + (b*TT + qbase + l15)*512 + h*32 + 8*g);
    const short* kvcb = kvc32 + b*TT*32;
    const short* kvtb = kvcT + (b*KVD + l15)*TT;

    f32x4 lacc = {0.f,0.f,0.f,0.f};
    f32x4 u    = {0.f,0.f,0.f,0.f};
    const f32x4 zf = {0.f,0.f,0.f,0.f};
    int nblk = (qbase + 47) >> 5;        // kv blocks of 32 covering [0, qbase+16)
    for (int kb = 0; kb < nblk; ++kb) {
        int kv0 = kb << 5;
        short8 kf0 = *(const short8*)(kvcb + (kv0 + l15)*32 + 8*g);
        short8 kf1 = *(const short8*)(kvcb + (kv0 + 16 + l15)*32 + 8*g);
        f32x4 s0 = __builtin_amdgcn_mfma_f32_16x16x32_bf16(qa, kf0, zf, 0, 0, 0);
        f32x4 s1 = __builtin_amdgcn_mfma_f32_16x16x32_bf16(qa, kf1, zf, 0, 0, 0);
        if (kv0 + 31 > qbase) {          // diagonal block(s): mask col > row
            #pragma unroll
            for (int r = 0; r < 4; ++r) {
                int row = qbase + 4*g + r;
                if (kv0 + l15 > row)      s0[r] = -INFINITY;
                if (kv0 + 16 + l15 > row) s1[r] = -INFINITY;
            }
        }
        #pragma unroll
        for (int r = 0; r < 4; ++r) {
            float p0 = exp2f(s0[r]);     // exp2(-inf) = 0 handles mask
            float p1 = exp2f(s1[r]);
            lacc[r] += p0 + p1;
            pl[4*g + r][l15]      = f2bf(p0);
            pl[4*g + r][16 + l15] = f2bf(p1);
        }
        asm volatile("s_waitcnt lgkmcnt(0)" ::: "memory");  // wave-local LDS transpose fence
        short8 pa = *(const short8*)(&pl[l15][8*g]);
        short8 vb = *(const short8*)(kvtb + kv0 + 8*g);
        u = __builtin_amdgcn_mfma_f32_16x16x32_bf16(pa, vb, u, 0, 0, 0);
    }
    #pragma unroll
    for (int off = 1; off < 16; off <<= 1) {
        #pragma unroll
        for (int r = 0; r < 4; ++r) lacc[r] += __shfl_xor(lacc[r], off);
    }
    #pragma unroll
    for (int r = 0; r < 4; ++r) {
        int row = b*TT + qbase + 4*g + r;
        u_bf[row*QP + h*KVD + l15] = f2bf(u[r] / lacc[r]);
    }
}

// ---------------- output GEMM: out = U @ Wvo + bop ----------------
__global__ __launch_bounds__(256) void ogemm(
    const short* __restrict__ u_bf, const short* __restrict__ Wvot,
    const float* __restrict__ bop, float* __restrict__ out)
{
    int bid = blockIdx.x;
    int w = threadIdx.x >> 6, lane = threadIdx.x & 63;
    int l15 = lane & 15, g = lane >> 4;
    int m0 = (bid >> 4)*64 + w*16;
    int nb = (bid & 15)*64;
    f32x4 acc[4];
    #pragma unroll
    for (int nt = 0; nt < 4; ++nt) acc[nt] = (f32x4){0.f,0.f,0.f,0.f};
    const short* arow = u_bf + (m0 + l15)*QP + 8*g;
    for (int k0 = 0; k0 < QP; k0 += 32) {
        short8 a = *(const short8*)(arow + k0);
        #pragma unroll
        for (int nt = 0; nt < 4; ++nt) {
            short8 bfr = *(const short8*)(Wvot + (nb + nt*16 + l15)*QP + k0 + 8*g);
            acc[nt] = __builtin_amdgcn_mfma_f32_16x16x32_bf16(a, bfr, acc[nt], 0, 0, 0);
        }
    }
    #pragma unroll
    for (int nt = 0; nt < 4; ++nt) {
        int n = nb + nt*16 + l15;
        float bias = bop[n];
        #pragma unroll
        for (int r = 0; r < 4; ++r)
            out[(m0 + 4*g + r)*DM + n] = acc[nt][r] + bias;
    }
}

extern "C" void kernel_launch(void* const* d_in, const int* in_sizes, int n_in,
                              void* d_out, int out_size, void* d_ws, size_t ws_size,
                              hipStream_t stream) {
    const float* x  = (const float*)d_in[0];
    const float* Wc = (const float*)d_in[1];
    const float* bc = (const float*)d_in[2];
    const float* Wk = (const float*)d_in[3];
    // d_in[4] = bk: drops out of softmax (constant per row)
    const float* Wv = (const float*)d_in[5];
    const float* bv = (const float*)d_in[6];
    const float* Wq = (const float*)d_in[7];
    const float* bq = (const float*)d_in[8];
    const float* Wo = (const float*)d_in[9];
    const float* bo = (const float*)d_in[10];
    // d_in[11] = mask: causal, implemented directly
    float* out = (float*)d_out;

    char* ws = (char*)d_ws;                       // needs 16 MiB
    short* x_bf  = (short*)(ws);                              // 8 MiB
    short* Wqt   = (short*)(ws + (8u<<20));                   // 512 KiB
    short* Wvot  = (short*)(ws + (8u<<20) + (512u<<10));      // 512 KiB
    float* bqp   = (float*)(ws + (9u<<20));                   // 1 KiB
    float* bop   = (float*)(ws + (9u<<20) + 4096);            // 4 KiB
    short* kvc32 = (short*)(ws + (9u<<20) + (512u<<10));      // 256 KiB
    short* kvcT  = (short*)(ws + (9u<<20) + (768u<<10));      // 128 KiB
    short* q32   = (short*)(ws + (10u<<20));                  // 4 MiB
    short* u_bf  = (short*)(ws + (14u<<20));                  // 2 MiB

    hipLaunchKernelGGL(prep_w, dim3(277),  dim3(256), 0, stream,
                       Wk, Wv, Wq, bq, Wo, bv, bo, Wqt, Wvot, bqp, bop);
    hipLaunchKernelGGL(prep_x, dim3(1024), dim3(256), 0, stream,
                       x, Wc, bc, x_bf, kvc32, kvcT);
    hipLaunchKernelGGL(qgemm,  dim3(1024), dim3(256), 0, stream,
                       x_bf, Wqt, bqp, q32);
    hipLaunchKernelGGL(attn,   dim3(1024), dim3(256), 0, stream,
                       q32, kvc32, kvcT, u_bf);
    hipLaunchKernelGGL(ogemm,  dim3(1024), dim3(256), 0, stream,
                       u_bf, Wvot, bop, out);
}

// Round 2
// 146.837 us; speedup vs baseline: 1.2183x; 1.2183x over previous
//
#include <hip/hip_runtime.h>
#include <hip/hip_bf16.h>
#include <math.h>

// Problem constants
#define TT 2048
#define BB 2
#define DM 1024
#define NH 16
#define HD 64
#define KVD 16
#define BT (BB*TT)   // 4096 rows total
#define QP 256       // NH*KVD

typedef short short8  __attribute__((ext_vector_type(8)));
typedef short short4v __attribute__((ext_vector_type(4)));
typedef float f32x4   __attribute__((ext_vector_type(4)));

static __device__ __forceinline__ short f2bf(float f) {
    union { float f; unsigned u; } v; v.f = f;
    unsigned r = v.u + 0x7fffu + ((v.u >> 16) & 1u);   // round-to-nearest-even
    return (short)(r >> 16);
}

// ---------------- prep 1a: Wqt (absorbed Q@K^T weight) + bqp ----------------
// Wqt[c][d] = bf16( log2e/8 * sum_e Wq[d][h*64+e]*Wk[j][h*64+e] ), c = h*16+j
// bqp[c]    = log2e/8 * sum_e bq[h*64+e]*Wk[j][h*64+e]
// grid: 16 h x 16 d-tiles of 64 rows = 256 blocks
__global__ __launch_bounds__(256) void prep_w1(
    const float* __restrict__ Wq, const float* __restrict__ Wk,
    const float* __restrict__ bq,
    short* __restrict__ Wqt, float* __restrict__ bqp)
{
    const float SC = 0.18033688011112042f;  // log2(e)/8
    int h = blockIdx.x >> 4, dt = blockIdx.x & 15;
    int d0 = dt * 64, tid = threadIdx.x;
    __shared__ float wk[16][64];
    __shared__ float wq[64][65];            // +1 pad: lanes read wq[r][e], r=lane
    for (int idx = tid; idx < 1024; idx += 256) {
        int j = idx >> 6, e = idx & 63;
        wk[j][e] = Wk[j*DM + h*HD + e];
    }
    #pragma unroll
    for (int i = 0; i < 16; ++i) {
        int idx = i*256 + tid;
        int r = idx >> 6, e = idx & 63;
        wq[r][e] = Wq[(d0 + r)*DM + h*HD + e];
    }
    __syncthreads();
    int r = tid & 63, j0 = (tid >> 6) * 4;
    float a0=0.f, a1=0.f, a2=0.f, a3=0.f;
    #pragma unroll 8
    for (int e = 0; e < 64; ++e) {
        float a = wq[r][e];
        a0 += a * wk[j0+0][e];
        a1 += a * wk[j0+1][e];
        a2 += a * wk[j0+2][e];
        a3 += a * wk[j0+3][e];
    }
    Wqt[(h*16 + j0+0)*DM + d0 + r] = f2bf(a0 * SC);
    Wqt[(h*16 + j0+1)*DM + d0 + r] = f2bf(a1 * SC);
    Wqt[(h*16 + j0+2)*DM + d0 + r] = f2bf(a2 * SC);
    Wqt[(h*16 + j0+3)*DM + d0 + r] = f2bf(a3 * SC);
    if (dt == 0 && tid < 16) {
        int j = tid;
        float acc = 0.f;
        #pragma unroll 8
        for (int e = 0; e < 64; ++e) acc += bq[h*HD + e] * wk[j][e];
        bqp[h*16 + j] = acc * SC;
    }
}

// ---------------- prep 1b: Wvot (absorbed V@Wo weight) + bop partials ----------------
// Wvot[n][h*16+j] = bf16( sum_e Wv[j][h*64+e]*Wo[h*64+e][n] )
// bop_part[h][n]  = sum_e bv[h*64+e]*Wo[h*64+e][n]   (fused on same Wo reads)
// grid: 16 h x 4 n-tiles of 256 = 64 blocks
__global__ __launch_bounds__(256) void prep_w2(
    const float* __restrict__ Wv, const float* __restrict__ Wo,
    const float* __restrict__ bv,
    short* __restrict__ Wvot, float* __restrict__ bop_part)
{
    int h = blockIdx.x >> 2, nt = blockIdx.x & 3;
    int tid = threadIdx.x, n = nt*256 + tid;
    __shared__ float wv[16][64];
    __shared__ float bvs[64];
    for (int idx = tid; idx < 1024; idx += 256) {
        int j = idx >> 6, e = idx & 63;
        wv[j][e] = Wv[j*DM + h*HD + e];
    }
    if (tid < 64) bvs[tid] = bv[h*HD + tid];
    __syncthreads();
    float acc[16];
    #pragma unroll
    for (int j = 0; j < 16; ++j) acc[j] = 0.f;
    float bacc = 0.f;
    #pragma unroll 4
    for (int e = 0; e < 64; ++e) {
        float wo = Wo[(h*HD + e)*DM + n];
        bacc += bvs[e] * wo;
        #pragma unroll
        for (int j = 0; j < 16; ++j) acc[j] += wv[j][e] * wo;
    }
    short8 o0, o1;
    #pragma unroll
    for (int j = 0; j < 8; ++j) { o0[j] = f2bf(acc[j]); o1[j] = f2bf(acc[j+8]); }
    *(short8*)(Wvot + n*QP + h*16)     = o0;
    *(short8*)(Wvot + n*QP + h*16 + 8) = o1;
    bop_part[h*DM + n] = bacc;
}

// ---------------- prep 2: x -> bf16, kvc (latent); tail blocks: bop reduce ----------------
// kvc32: [BT][32] bf16, latent padded with zeros (QK B-side)
// kvcT : [B][16][T] bf16 (PV B-side)
__global__ __launch_bounds__(256) void prep_x(
    const float* __restrict__ x, const float* __restrict__ Wc,
    const float* __restrict__ bc,
    short* __restrict__ x_bf, short* __restrict__ kvc32, short* __restrict__ kvcT,
    const float* __restrict__ bo, const float* __restrict__ bop_part,
    float* __restrict__ bop)
{
    if (blockIdx.x >= 1024) {               // bop reduce (prep_w2 precedes in stream)
        int n = (blockIdx.x - 1024)*256 + threadIdx.x;
        float s = bo[n];
        #pragma unroll
        for (int h = 0; h < 16; ++h) s += bop_part[h*DM + n];
        bop[n] = s;
        return;
    }
    int t0 = blockIdx.x * 4, tid = threadIdx.x;
    __shared__ float xs[4][DM];
    __shared__ float part[4][16][17];
    #pragma unroll
    for (int i = 0; i < 4; ++i) {
        float4 xv = *(const float4*)(x + (t0+i)*DM + tid*4);
        *(float4*)(&xs[i][tid*4]) = xv;
        short4v xb;
        xb[0]=f2bf(xv.x); xb[1]=f2bf(xv.y); xb[2]=f2bf(xv.z); xb[3]=f2bf(xv.w);
        *(short4v*)(x_bf + (t0+i)*DM + tid*4) = xb;
    }
    __syncthreads();
    int g = tid >> 4, n = tid & 15;
    float a0=0.f, a1=0.f, a2=0.f, a3=0.f;
    #pragma unroll 4
    for (int k = 0; k < 64; ++k) {
        float wc = Wc[(g*64 + k)*KVD + n];
        a0 += xs[0][g*64+k]*wc; a1 += xs[1][g*64+k]*wc;
        a2 += xs[2][g*64+k]*wc; a3 += xs[3][g*64+k]*wc;
    }
    part[0][g][n]=a0; part[1][g][n]=a1; part[2][g][n]=a2; part[3][g][n]=a3;
    __syncthreads();
    if (tid < 64) {
        int i = tid >> 4, nn = tid & 15;
        float s = bc[nn];
        #pragma unroll
        for (int gg = 0; gg < 16; ++gg) s += part[i][gg][nn];
        short v = f2bf(s);
        int t = t0 + i;
        kvc32[t*32 + nn]      = v;
        kvc32[t*32 + 16 + nn] = 0;
        int b = t >> 11, tl = t & (TT-1);
        kvcT[(b*KVD + nn)*TT + tl] = v;
    }
}

// ---------------- q' GEMM: q32 = (x @ Wq' + bq') * log2e/8, padded to 32/head ----------------
__global__ __launch_bounds__(256) void qgemm(
    const short* __restrict__ x_bf, const short* __restrict__ Wqt,
    const float* __restrict__ bqp, short* __restrict__ q32)
{
    int bid = blockIdx.x;
    int w = threadIdx.x >> 6, lane = threadIdx.x & 63;
    int l15 = lane & 15, g = lane >> 4;
    int m0 = (bid >> 4)*64 + w*16;
    int nb = (bid & 15)*16;
    f32x4 acc = {0.f,0.f,0.f,0.f};
    const short* arow = x_bf + (m0 + l15)*DM + 8*g;
    const short* brow = Wqt  + (nb + l15)*DM + 8*g;
    for (int k0 = 0; k0 < DM; k0 += 32) {
        short8 a = *(const short8*)(arow + k0);
        short8 b = *(const short8*)(brow + k0);
        acc = __builtin_amdgcn_mfma_f32_16x16x32_bf16(a, b, acc, 0, 0, 0);
    }
    int c = nb + l15;
    float bias = bqp[c];
    int co = (c >> 4)*32 + l15;
    #pragma unroll
    for (int r = 0; r < 4; ++r) {
        int row = m0 + 4*g + r;
        q32[row*512 + co]      = f2bf(acc[r] + bias);
        q32[row*512 + co + 16] = 0;
    }
}

// ---------------- causal latent attention ----------------
// Per wave: 16 q rows of one (b,h). S tile via mfma(A=q32, B=kvc32), K=32 (latent 16 + zero pad).
// No max-subtraction (|S*log2e| small): P = exp2(S), denominator accumulated per-lane.
// P -> A-frag via per-wave LDS [16][40] tile; PV: U += P @ kvc (B-frag from kvcT).
__global__ __launch_bounds__(256) void attn(
    const short* __restrict__ q32, const short* __restrict__ kvc32,
    const short* __restrict__ kvcT, short* __restrict__ u_bf)
{
    int bid = blockIdx.x;
    int r5 = bid >> 5;
    int aa = r5 & 7, b2 = r5 >> 3;
    // balance causal triangle across CUs: each CU's 4 blocks get complementary lengths
    int qb = (b2 & 1) ? (31 - 2*aa - (b2 >> 1)) : (2*aa + (b2 >> 1));
    int bh = bid & 31, b = bh >> 4, h = bh & 15;
    int w = threadIdx.x >> 6, lane = threadIdx.x & 63;
    int l15 = lane & 15, g = lane >> 4;
    int qbase = qb*64 + w*16;
    __shared__ short p_lds[4][16][40];   // per-wave P tile, padded rows (80B) for banks
    short (*pl)[40] = p_lds[w];

    short8 qa = *(const short8*)(q32 + (b*TT + qbase + l15)*512 + h*32 + 8*g);
    const short* kvcb = kvc32 + b*TT*32;
    const short* kvtb = kvcT + (b*KVD + l15)*TT;

    f32x4 lacc = {0.f,0.f,0.f,0.f};
    f32x4 u    = {0.f,0.f,0.f,0.f};
    const f32x4 zf = {0.f,0.f,0.f,0.f};
    int nblk = (qbase + 47) >> 5;        // kv blocks of 32 covering [0, qbase+16)
    for (int kb = 0; kb < nblk; ++kb) {
        int kv0 = kb << 5;
        short8 kf0 = *(const short8*)(kvcb + (kv0 + l15)*32 + 8*g);
        short8 kf1 = *(const short8*)(kvcb + (kv0 + 16 + l15)*32 + 8*g);
        f32x4 s0 = __builtin_amdgcn_mfma_f32_16x16x32_bf16(qa, kf0, zf, 0, 0, 0);
        f32x4 s1 = __builtin_amdgcn_mfma_f32_16x16x32_bf16(qa, kf1, zf, 0, 0, 0);
        if (kv0 + 31 > qbase) {          // diagonal block(s): mask col > row
            #pragma unroll
            for (int r = 0; r < 4; ++r) {
                int row = qbase + 4*g + r;
                if (kv0 + l15 > row)      s0[r] = -INFINITY;
                if (kv0 + 16 + l15 > row) s1[r] = -INFINITY;
            }
        }
        #pragma unroll
        for (int r = 0; r < 4; ++r) {
            float p0 = exp2f(s0[r]);     // exp2(-inf) = 0 handles mask
            float p1 = exp2f(s1[r]);
            lacc[r] += p0 + p1;
            pl[4*g + r][l15]      = f2bf(p0);
            pl[4*g + r][16 + l15] = f2bf(p1);
        }
        asm volatile("s_waitcnt lgkmcnt(0)" ::: "memory");  // wave-local LDS transpose fence
        short8 pa = *(const short8*)(&pl[l15][8*g]);
        short8 vb = *(const short8*)(kvtb + kv0 + 8*g);
        u = __builtin_amdgcn_mfma_f32_16x16x32_bf16(pa, vb, u, 0, 0, 0);
    }
    #pragma unroll
    for (int off = 1; off < 16; off <<= 1) {
        #pragma unroll
        for (int r = 0; r < 4; ++r) lacc[r] += __shfl_xor(lacc[r], off);
    }
    #pragma unroll
    for (int r = 0; r < 4; ++r) {
        int row = b*TT + qbase + 4*g + r;
        u_bf[row*QP + h*KVD + l15] = f2bf(u[r] / lacc[r]);
    }
}

// ---------------- output GEMM: out = U @ Wvo + bop ----------------
__global__ __launch_bounds__(256) void ogemm(
    const short* __restrict__ u_bf, const short* __restrict__ Wvot,
    const float* __restrict__ bop, float* __restrict__ out)
{
    int bid = blockIdx.x;
    int w = threadIdx.x >> 6, lane = threadIdx.x & 63;
    int l15 = lane & 15, g = lane >> 4;
    int m0 = (bid >> 4)*64 + w*16;
    int nb = (bid & 15)*64;
    f32x4 acc[4];
    #pragma unroll
    for (int nt = 0; nt < 4; ++nt) acc[nt] = (f32x4){0.f,0.f,0.f,0.f};
    const short* arow = u_bf + (m0 + l15)*QP + 8*g;
    for (int k0 = 0; k0 < QP; k0 += 32) {
        short8 a = *(const short8*)(arow + k0);
        #pragma unroll
        for (int nt = 0; nt < 4; ++nt) {
            short8 bfr = *(const short8*)(Wvot + (nb + nt*16 + l15)*QP + k0 + 8*g);
            acc[nt] = __builtin_amdgcn_mfma_f32_16x16x32_bf16(a, bfr, acc[nt], 0, 0, 0);
        }
    }
    #pragma unroll
    for (int nt = 0; nt < 4; ++nt) {
        int n = nb + nt*16 + l15;
        float bias = bop[n];
        #pragma unroll
        for (int r = 0; r < 4; ++r)
            out[(m0 + 4*g + r)*DM + n] = acc[nt][r] + bias;
    }
}

extern "C" void kernel_launch(void* const* d_in, const int* in_sizes, int n_in,
                              void* d_out, int out_size, void* d_ws, size_t ws_size,
                              hipStream_t stream) {
    const float* x  = (const float*)d_in[0];
    const float* Wc = (const float*)d_in[1];
    const float* bc = (const float*)d_in[2];
    const float* Wk = (const float*)d_in[3];
    // d_in[4] = bk: drops out of softmax (constant per row)
    const float* Wv = (const float*)d_in[5];
    const float* bv = (const float*)d_in[6];
    const float* Wq = (const float*)d_in[7];
    const float* bq = (const float*)d_in[8];
    const float* Wo = (const float*)d_in[9];
    const float* bo = (const float*)d_in[10];
    // d_in[11] = mask: causal, implemented directly
    float* out = (float*)d_out;

    char* ws = (char*)d_ws;                       // needs 16 MiB
    short* x_bf     = (short*)(ws);                              // 8 MiB
    short* Wqt      = (short*)(ws + (8u<<20));                   // 512 KiB
    short* Wvot     = (short*)(ws + (8u<<20) + (512u<<10));      // 512 KiB
    float* bqp      = (float*)(ws + (9u<<20));                   // 1 KiB
    float* bop      = (float*)(ws + (9u<<20) + 4096);            // 4 KiB
    float* bop_part = (float*)(ws + (9u<<20) + 8192);            // 64 KiB
    short* kvc32    = (short*)(ws + (9u<<20) + (512u<<10));      // 256 KiB
    short* kvcT     = (short*)(ws + (9u<<20) + (768u<<10));      // 128 KiB
    short* q32      = (short*)(ws + (10u<<20));                  // 4 MiB
    short* u_bf     = (short*)(ws + (14u<<20));                  // 2 MiB

    hipLaunchKernelGGL(prep_w1, dim3(256),  dim3(256), 0, stream,
                       Wq, Wk, bq, Wqt, bqp);
    hipLaunchKernelGGL(prep_w2, dim3(64),   dim3(256), 0, stream,
                       Wv, Wo, bv, Wvot, bop_part);
    hipLaunchKernelGGL(prep_x,  dim3(1028), dim3(256), 0, stream,
                       x, Wc, bc, x_bf, kvc32, kvcT, bo, bop_part, bop);
    hipLaunchKernelGGL(qgemm,   dim3(1024), dim3(256), 0, stream,
                       x_bf, Wqt, bqp, q32);
    hipLaunchKernelGGL(attn,    dim3(1024), dim3(256), 0, stream,
                       q32, kvc32, kvcT, u_bf);
    hipLaunchKernelGGL(ogemm,   dim3(1024), dim3(256), 0, stream,
                       u_bf, Wvot, bop, out);
}

// Round 3
// 128.386 us; speedup vs baseline: 1.3934x; 1.1437x over previous
//
#include <hip/hip_runtime.h>
#include <hip/hip_bf16.h>
#include <math.h>

// Problem constants
#define TT 2048
#define BB 2
#define DM 1024
#define NH 16
#define HD 64
#define KVD 16
#define BT (BB*TT)   // 4096 rows total
#define QP 256       // NH*KVD

typedef short short8  __attribute__((ext_vector_type(8)));
typedef short short4v __attribute__((ext_vector_type(4)));
typedef float f32x4   __attribute__((ext_vector_type(4)));
typedef float f32x16  __attribute__((ext_vector_type(16)));

static __device__ __forceinline__ short f2bf(float f) {
    union { float f; unsigned u; } v; v.f = f;
    unsigned r = v.u + 0x7fffu + ((v.u >> 16) & 1u);   // round-to-nearest-even
    return (short)(r >> 16);
}

// ---------------- prep 1a: Wqt (absorbed Q@K^T weight) + bqp ----------------
__global__ __launch_bounds__(256) void prep_w1(
    const float* __restrict__ Wq, const float* __restrict__ Wk,
    const float* __restrict__ bq,
    short* __restrict__ Wqt, float* __restrict__ bqp)
{
    const float SC = 0.18033688011112042f;  // log2(e)/8
    int h = blockIdx.x >> 4, dt = blockIdx.x & 15;
    int d0 = dt * 64, tid = threadIdx.x;
    __shared__ float wk[16][64];
    __shared__ float wq[64][65];
    for (int idx = tid; idx < 1024; idx += 256) {
        int j = idx >> 6, e = idx & 63;
        wk[j][e] = Wk[j*DM + h*HD + e];
    }
    #pragma unroll
    for (int i = 0; i < 16; ++i) {
        int idx = i*256 + tid;
        int r = idx >> 6, e = idx & 63;
        wq[r][e] = Wq[(d0 + r)*DM + h*HD + e];
    }
    __syncthreads();
    int r = tid & 63, j0 = (tid >> 6) * 4;
    float a0=0.f, a1=0.f, a2=0.f, a3=0.f;
    #pragma unroll 8
    for (int e = 0; e < 64; ++e) {
        float a = wq[r][e];
        a0 += a * wk[j0+0][e];
        a1 += a * wk[j0+1][e];
        a2 += a * wk[j0+2][e];
        a3 += a * wk[j0+3][e];
    }
    Wqt[(h*16 + j0+0)*DM + d0 + r] = f2bf(a0 * SC);
    Wqt[(h*16 + j0+1)*DM + d0 + r] = f2bf(a1 * SC);
    Wqt[(h*16 + j0+2)*DM + d0 + r] = f2bf(a2 * SC);
    Wqt[(h*16 + j0+3)*DM + d0 + r] = f2bf(a3 * SC);
    if (dt == 0 && tid < 16) {
        int j = tid;
        float acc = 0.f;
        #pragma unroll 8
        for (int e = 0; e < 64; ++e) acc += bq[h*HD + e] * wk[j][e];
        bqp[h*16 + j] = acc * SC;
    }
}

// ---------------- prep 1b: Wvot (absorbed V@Wo weight) + bop partials ----------------
__global__ __launch_bounds__(256) void prep_w2(
    const float* __restrict__ Wv, const float* __restrict__ Wo,
    const float* __restrict__ bv,
    short* __restrict__ Wvot, float* __restrict__ bop_part)
{
    int h = blockIdx.x >> 2, nt = blockIdx.x & 3;
    int tid = threadIdx.x, n = nt*256 + tid;
    __shared__ float wv[16][64];
    __shared__ float bvs[64];
    for (int idx = tid; idx < 1024; idx += 256) {
        int j = idx >> 6, e = idx & 63;
        wv[j][e] = Wv[j*DM + h*HD + e];
    }
    if (tid < 64) bvs[tid] = bv[h*HD + tid];
    __syncthreads();
    float acc[16];
    #pragma unroll
    for (int j = 0; j < 16; ++j) acc[j] = 0.f;
    float bacc = 0.f;
    #pragma unroll 4
    for (int e = 0; e < 64; ++e) {
        float wo = Wo[(h*HD + e)*DM + n];
        bacc += bvs[e] * wo;
        #pragma unroll
        for (int j = 0; j < 16; ++j) acc[j] += wv[j][e] * wo;
    }
    short8 o0, o1;
    #pragma unroll
    for (int j = 0; j < 8; ++j) { o0[j] = f2bf(acc[j]); o1[j] = f2bf(acc[j+8]); }
    *(short8*)(Wvot + n*QP + h*16)     = o0;
    *(short8*)(Wvot + n*QP + h*16 + 8) = o1;
    bop_part[h*DM + n] = bacc;
}

// ---------------- prep 2: x -> bf16, kvc latent [BT][16] + kvcT [B][32][T]; tail: bop ----------------
__global__ __launch_bounds__(256) void prep_x(
    const float* __restrict__ x, const float* __restrict__ Wc,
    const float* __restrict__ bc,
    short* __restrict__ x_bf, short* __restrict__ kvc16, short* __restrict__ kvcT,
    const float* __restrict__ bo, const float* __restrict__ bop_part,
    float* __restrict__ bop)
{
    if (blockIdx.x >= 1024) {               // bop reduce (prep_w2 precedes in stream)
        int n = (blockIdx.x - 1024)*256 + threadIdx.x;
        float s = bo[n];
        #pragma unroll
        for (int h = 0; h < 16; ++h) s += bop_part[h*DM + n];
        bop[n] = s;
        return;
    }
    int t0 = blockIdx.x * 4, tid = threadIdx.x;
    __shared__ float xs[4][DM];
    __shared__ float part[4][16][17];
    #pragma unroll
    for (int i = 0; i < 4; ++i) {
        float4 xv = *(const float4*)(x + (t0+i)*DM + tid*4);
        *(float4*)(&xs[i][tid*4]) = xv;
        short4v xb;
        xb[0]=f2bf(xv.x); xb[1]=f2bf(xv.y); xb[2]=f2bf(xv.z); xb[3]=f2bf(xv.w);
        *(short4v*)(x_bf + (t0+i)*DM + tid*4) = xb;
    }
    __syncthreads();
    int g = tid >> 4, n = tid & 15;
    float a0=0.f, a1=0.f, a2=0.f, a3=0.f;
    #pragma unroll 4
    for (int k = 0; k < 64; ++k) {
        float wc = Wc[(g*64 + k)*KVD + n];
        a0 += xs[0][g*64+k]*wc; a1 += xs[1][g*64+k]*wc;
        a2 += xs[2][g*64+k]*wc; a3 += xs[3][g*64+k]*wc;
    }
    part[0][g][n]=a0; part[1][g][n]=a1; part[2][g][n]=a2; part[3][g][n]=a3;
    __syncthreads();
    if (tid < 64) {
        int i = tid >> 4, nn = tid & 15;
        float s = bc[nn];
        #pragma unroll
        for (int gg = 0; gg < 16; ++gg) s += part[i][gg][nn];
        short v = f2bf(s);
        int t = t0 + i;
        kvc16[t*16 + nn] = v;
        int b = t >> 11, tl = t & (TT-1);
        kvcT[(b*32 + nn)*TT + tl]      = v;
        kvcT[(b*32 + 16 + nn)*TT + tl] = 0;   // zero pad rows 16..31
    }
}

// ---------------- q' GEMM: q16 = (x @ Wq' + bq'), [BT][256] bf16 ----------------
__global__ __launch_bounds__(256) void qgemm(
    const short* __restrict__ x_bf, const short* __restrict__ Wqt,
    const float* __restrict__ bqp, short* __restrict__ q16)
{
    int bid = blockIdx.x;
    int w = threadIdx.x >> 6, lane = threadIdx.x & 63;
    int l15 = lane & 15, g = lane >> 4;
    int m0 = (bid >> 4)*64 + w*16;
    int nb = (bid & 15)*16;
    f32x4 acc = {0.f,0.f,0.f,0.f};
    const short* arow = x_bf + (m0 + l15)*DM + 8*g;
    const short* brow = Wqt  + (nb + l15)*DM + 8*g;
    for (int k0 = 0; k0 < DM; k0 += 32) {
        short8 a = *(const short8*)(arow + k0);
        short8 b = *(const short8*)(brow + k0);
        acc = __builtin_amdgcn_mfma_f32_16x16x32_bf16(a, b, acc, 0, 0, 0);
    }
    int c = nb + l15;
    float bias = bqp[c];
    #pragma unroll
    for (int r = 0; r < 4; ++r) {
        int row = m0 + 4*g + r;
        q16[row*QP + c] = f2bf(acc[r] + bias);
    }
}

// ---------------- causal latent attention, 32x32 swapped MFMA ----------------
// Block = one (b,h,32-row q-tile); 4 waves split the KV range; additive combine
// (no-max softmax => partial U and D just add). Inner loop has NO LDS.
// S^T = mfma_32x32x16(K, Q): lane holds col q = lane&31, rows kv = (r&3)+8*(r>>2)+4*hi.
// P packed to bf16 pairs (cvt_pk), cross-half exchange (shfl_xor 32) -> PV A-frags.
// PV: U += P[:,16c:16c+16] @ V-chunk via mfma_32x32x16 (lat cols 16..31 discarded).
__global__ __launch_bounds__(256) void attn(
    const short* __restrict__ q16, const short* __restrict__ kvc16,
    const short* __restrict__ kvcT, short* __restrict__ u_bf)
{
    int bid = blockIdx.x;
    int s = bid >> 5, bh = bid & 31;
    int qt = (s & 1) ? (63 - (s >> 1)) : (s >> 1);   // causal balance pairing
    int b = bh >> 4, h = bh & 15;
    int w = threadIdx.x >> 6, lane = threadIdx.x & 63;
    int l31 = lane & 31, hi = lane >> 5;
    int qbase = qt * 32;

    __shared__ float ulds[4][32][17];
    __shared__ float dlds[4][32];

    // Q B-frag (loaded once): B[k][j]: j = l31 = q col, k = 8*hi + e (latent)
    short8 qf = *(const short8*)(q16 + (b*TT + qbase + l31)*QP + h*16 + 8*hi);
    const short* kbase = kvc16 + (b*TT + l31)*16 + 8*hi;
    const short* vrow  = kvcT + (b*32 + l31)*TT;

    int ntiles = qt + 1;
    int t0 = (w * ntiles) >> 2;
    int t1 = ((w + 1) * ntiles) >> 2;

    f32x16 u;
    f32x16 zf;
    #pragma unroll
    for (int r = 0; r < 16; ++r) { u[r] = 0.f; zf[r] = 0.f; }
    float lacc = 0.f;

    for (int kt = t0; kt < t1; ++kt) {
        int kv0 = kt << 5;
        short8 kf = *(const short8*)(kbase + kv0*16);
        f32x16 st = __builtin_amdgcn_mfma_f32_32x32x16_bf16(kf, qf, zf, 0, 0, 0);
        if (kt == qt) {                      // diagonal tile: mask kv > q
            #pragma unroll
            for (int r = 0; r < 16; ++r) {
                int kvl = (r & 3) + 8*(r >> 2) + 4*hi;
                if (kvl > l31) st[r] = -INFINITY;
            }
        }
        float p[16];
        #pragma unroll
        for (int r = 0; r < 16; ++r) { p[r] = exp2f(st[r]); lacc += p[r]; }
        // pack pairs: wd[i] = bf16x2(p[2i], p[2i+1]); lane holds kv = 8j+4hi+2m+{0,1}, i=2j+m
        int wd[8];
        #pragma unroll
        for (int i = 0; i < 8; ++i) {
            asm("v_cvt_pk_bf16_f32 %0, %1, %2" : "=v"(wd[i]) : "v"(p[2*i]), "v"(p[2*i+1]));
        }
        // cross-half exchange -> A-frag words for kv 16c+8hi+{0..7}
        int fa[2][4];
        #pragma unroll
        for (int c = 0; c < 2; ++c) {
            int o0 = __shfl_xor(wd[4*c+0], 32, 64);
            int o1 = __shfl_xor(wd[4*c+1], 32, 64);
            int o2 = __shfl_xor(wd[4*c+2], 32, 64);
            int o3 = __shfl_xor(wd[4*c+3], 32, 64);
            fa[c][0] = hi ? o2 : wd[4*c+0];
            fa[c][1] = hi ? o3 : wd[4*c+1];
            fa[c][2] = hi ? wd[4*c+2] : o0;
            fa[c][3] = hi ? wd[4*c+3] : o1;
        }
        union { int i4[4]; short8 s8; } pa0, pa1;
        pa0.i4[0]=fa[0][0]; pa0.i4[1]=fa[0][1]; pa0.i4[2]=fa[0][2]; pa0.i4[3]=fa[0][3];
        pa1.i4[0]=fa[1][0]; pa1.i4[1]=fa[1][1]; pa1.i4[2]=fa[1][2]; pa1.i4[3]=fa[1][3];
        short8 vb0 = *(const short8*)(vrow + kv0 + 8*hi);
        short8 vb1 = *(const short8*)(vrow + kv0 + 16 + 8*hi);
        u = __builtin_amdgcn_mfma_f32_32x32x16_bf16(pa0.s8, vb0, u, 0, 0, 0);
        u = __builtin_amdgcn_mfma_f32_32x32x16_bf16(pa1.s8, vb1, u, 0, 0, 0);
    }

    // combine: per-wave partials are additive (no-max softmax)
    lacc += __shfl_xor(lacc, 32, 64);
    #pragma unroll
    for (int r = 0; r < 16; ++r) {
        int q = (r & 3) + 8*(r >> 2) + 4*hi;
        if (l31 < 16) ulds[w][q][l31] = u[r];
    }
    if (hi == 0) dlds[w][l31] = lacc;
    __syncthreads();
    int tid = threadIdx.x;
    #pragma unroll
    for (int e = 0; e < 2; ++e) {
        int idx = tid*2 + e;
        int q = idx >> 4, lat = idx & 15;
        float us = ulds[0][q][lat] + ulds[1][q][lat] + ulds[2][q][lat] + ulds[3][q][lat];
        float dd = dlds[0][q] + dlds[1][q] + dlds[2][q] + dlds[3][q];
        u_bf[(b*TT + qbase + q)*QP + h*16 + lat] = f2bf(us / dd);
    }
}

// ---------------- output GEMM: out = U @ Wvo + bop ----------------
__global__ __launch_bounds__(256) void ogemm(
    const short* __restrict__ u_bf, const short* __restrict__ Wvot,
    const float* __restrict__ bop, float* __restrict__ out)
{
    int bid = blockIdx.x;
    int w = threadIdx.x >> 6, lane = threadIdx.x & 63;
    int l15 = lane & 15, g = lane >> 4;
    int m0 = (bid >> 4)*64 + w*16;
    int nb = (bid & 15)*64;
    f32x4 acc[4];
    #pragma unroll
    for (int nt = 0; nt < 4; ++nt) acc[nt] = (f32x4){0.f,0.f,0.f,0.f};
    const short* arow = u_bf + (m0 + l15)*QP + 8*g;
    for (int k0 = 0; k0 < QP; k0 += 32) {
        short8 a = *(const short8*)(arow + k0);
        #pragma unroll
        for (int nt = 0; nt < 4; ++nt) {
            short8 bfr = *(const short8*)(Wvot + (nb + nt*16 + l15)*QP + k0 + 8*g);
            acc[nt] = __builtin_amdgcn_mfma_f32_16x16x32_bf16(a, bfr, acc[nt], 0, 0, 0);
        }
    }
    #pragma unroll
    for (int nt = 0; nt < 4; ++nt) {
        int n = nb + nt*16 + l15;
        float bias = bop[n];
        #pragma unroll
        for (int r = 0; r < 4; ++r)
            out[(m0 + 4*g + r)*DM + n] = acc[nt][r] + bias;
    }
}

extern "C" void kernel_launch(void* const* d_in, const int* in_sizes, int n_in,
                              void* d_out, int out_size, void* d_ws, size_t ws_size,
                              hipStream_t stream) {
    const float* x  = (const float*)d_in[0];
    const float* Wc = (const float*)d_in[1];
    const float* bc = (const float*)d_in[2];
    const float* Wk = (const float*)d_in[3];
    // d_in[4] = bk: drops out of softmax (constant per row)
    const float* Wv = (const float*)d_in[5];
    const float* bv = (const float*)d_in[6];
    const float* Wq = (const float*)d_in[7];
    const float* bq = (const float*)d_in[8];
    const float* Wo = (const float*)d_in[9];
    const float* bo = (const float*)d_in[10];
    // d_in[11] = mask: causal, implemented directly
    float* out = (float*)d_out;

    char* ws = (char*)d_ws;                       // needs 16 MiB
    short* x_bf     = (short*)(ws);                              // 8 MiB
    short* Wqt      = (short*)(ws + (8u<<20));                   // 512 KiB
    short* Wvot     = (short*)(ws + (8u<<20) + (512u<<10));      // 512 KiB
    float* bqp      = (float*)(ws + (9u<<20));                   // 1 KiB
    float* bop      = (float*)(ws + (9u<<20) + 4096);            // 4 KiB
    float* bop_part = (float*)(ws + (9u<<20) + 8192);            // 64 KiB
    short* kvc16    = (short*)(ws + (9u<<20) + (512u<<10));      // 128 KiB
    short* kvcT     = (short*)(ws + (9u<<20) + (768u<<10));      // 256 KiB [B][32][T]
    short* q16      = (short*)(ws + (10u<<20));                  // 2 MiB [BT][256]
    short* u_bf     = (short*)(ws + (14u<<20));                  // 2 MiB

    hipLaunchKernelGGL(prep_w1, dim3(256),  dim3(256), 0, stream,
                       Wq, Wk, bq, Wqt, bqp);
    hipLaunchKernelGGL(prep_w2, dim3(64),   dim3(256), 0, stream,
                       Wv, Wo, bv, Wvot, bop_part);
    hipLaunchKernelGGL(prep_x,  dim3(1028), dim3(256), 0, stream,
                       x, Wc, bc, x_bf, kvc16, kvcT, bo, bop_part, bop);
    hipLaunchKernelGGL(qgemm,   dim3(1024), dim3(256), 0, stream,
                       x_bf, Wqt, bqp, q16);
    hipLaunchKernelGGL(attn,    dim3(2048), dim3(256), 0, stream,
                       q16, kvc16, kvcT, u_bf);
    hipLaunchKernelGGL(ogemm,   dim3(1024), dim3(256), 0, stream,
                       u_bf, Wvot, bop, out);
}

// Round 4
// 102.865 us; speedup vs baseline: 1.7391x; 1.2481x over previous
//
#include <hip/hip_runtime.h>
#include <hip/hip_bf16.h>
#include <math.h>

// Problem constants
#define TT 2048
#define BB 2
#define DM 1024
#define NH 16
#define HD 64
#define KVD 16
#define BT (BB*TT)   // 4096 rows total
#define QP 256       // NH*KVD

typedef short short8  __attribute__((ext_vector_type(8)));
typedef short short4v __attribute__((ext_vector_type(4)));
typedef float f32x4   __attribute__((ext_vector_type(4)));
typedef float f32x16  __attribute__((ext_vector_type(16)));

static __device__ __forceinline__ short f2bf(float f) {
    union { float f; unsigned u; } v; v.f = f;
    unsigned r = v.u + 0x7fffu + ((v.u >> 16) & 1u);   // round-to-nearest-even
    return (short)(r >> 16);
}

// ---------------- prep_all: absorbed weights + x->bf16 + latent kvc ----------------
// bid [0,256):    Wqt[c][d] = bf16(log2e/8 * Wq[d,h*64:]·Wk[j,h*64:]), c=h*16+j; bqp
// bid [256,320):  Wvot[n][h*16+j] = bf16(Wv[j,h*64:]·Wo[h*64:,n]); bop_part[h][n]
// bid [320,1344): x -> bf16; kvc16[t][16] = x[t]@Wc + bc; kvcT[b][32][T] (rows 16..31 zero)
__global__ __launch_bounds__(256) void prep_all(
    const float* __restrict__ Wq, const float* __restrict__ Wk,
    const float* __restrict__ bq,
    const float* __restrict__ Wv, const float* __restrict__ Wo,
    const float* __restrict__ bv,
    const float* __restrict__ x,  const float* __restrict__ Wc,
    const float* __restrict__ bc,
    short* __restrict__ Wqt, float* __restrict__ bqp,
    short* __restrict__ Wvot, float* __restrict__ bop_part,
    short* __restrict__ x_bf, short* __restrict__ kvc16, short* __restrict__ kvcT)
{
    __shared__ __align__(16) char smem[20736];
    int bid = blockIdx.x, tid = threadIdx.x;
    if (bid < 256) {
        // ---- Wqt + bqp ----
        const float SC = 0.18033688011112042f;  // log2(e)/8
        float (*wk)[64] = (float(*)[64])smem;            // 4096 B
        float (*wq)[65] = (float(*)[65])(smem + 4096);   // 16640 B
        int h = bid >> 4, dt = bid & 15;
        int d0 = dt * 64;
        for (int idx = tid; idx < 1024; idx += 256) {
            int j = idx >> 6, e = idx & 63;
            wk[j][e] = Wk[j*DM + h*HD + e];
        }
        #pragma unroll
        for (int i = 0; i < 16; ++i) {
            int idx = i*256 + tid;
            int r = idx >> 6, e = idx & 63;
            wq[r][e] = Wq[(d0 + r)*DM + h*HD + e];
        }
        __syncthreads();
        int r = tid & 63, j0 = (tid >> 6) * 4;
        float a0=0.f, a1=0.f, a2=0.f, a3=0.f;
        #pragma unroll 8
        for (int e = 0; e < 64; ++e) {
            float a = wq[r][e];
            a0 += a * wk[j0+0][e];
            a1 += a * wk[j0+1][e];
            a2 += a * wk[j0+2][e];
            a3 += a * wk[j0+3][e];
        }
        Wqt[(h*16 + j0+0)*DM + d0 + r] = f2bf(a0 * SC);
        Wqt[(h*16 + j0+1)*DM + d0 + r] = f2bf(a1 * SC);
        Wqt[(h*16 + j0+2)*DM + d0 + r] = f2bf(a2 * SC);
        Wqt[(h*16 + j0+3)*DM + d0 + r] = f2bf(a3 * SC);
        if (dt == 0 && tid < 16) {
            int j = tid;
            float acc = 0.f;
            #pragma unroll 8
            for (int e = 0; e < 64; ++e) acc += bq[h*HD + e] * wk[j][e];
            bqp[h*16 + j] = acc * SC;
        }
    } else if (bid < 320) {
        // ---- Wvot + bop_part ----
        float (*wv)[64] = (float(*)[64])smem;            // 4096 B
        float* bvs = (float*)(smem + 4096);              // 256 B
        int hb = bid - 256;
        int h = hb >> 2, nt = hb & 3;
        int n = nt*256 + tid;
        for (int idx = tid; idx < 1024; idx += 256) {
            int j = idx >> 6, e = idx & 63;
            wv[j][e] = Wv[j*DM + h*HD + e];
        }
        if (tid < 64) bvs[tid] = bv[h*HD + tid];
        __syncthreads();
        float acc[16];
        #pragma unroll
        for (int j = 0; j < 16; ++j) acc[j] = 0.f;
        float bacc = 0.f;
        #pragma unroll 4
        for (int e = 0; e < 64; ++e) {
            float wo = Wo[(h*HD + e)*DM + n];
            bacc += bvs[e] * wo;
            #pragma unroll
            for (int j = 0; j < 16; ++j) acc[j] += wv[j][e] * wo;
        }
        short8 o0, o1;
        #pragma unroll
        for (int j = 0; j < 8; ++j) { o0[j] = f2bf(acc[j]); o1[j] = f2bf(acc[j+8]); }
        *(short8*)(Wvot + n*QP + h*16)     = o0;
        *(short8*)(Wvot + n*QP + h*16 + 8) = o1;
        bop_part[h*DM + n] = bacc;
    } else {
        // ---- x -> bf16, kvc ----
        float (*xs)[DM]      = (float(*)[DM])smem;               // 16384 B
        float (*part)[16][17] = (float(*)[16][17])(smem + 16384); // 4352 B
        int t0 = (bid - 320) * 4;
        #pragma unroll
        for (int i = 0; i < 4; ++i) {
            float4 xv = *(const float4*)(x + (t0+i)*DM + tid*4);
            *(float4*)(&xs[i][tid*4]) = xv;
            short4v xb;
            xb[0]=f2bf(xv.x); xb[1]=f2bf(xv.y); xb[2]=f2bf(xv.z); xb[3]=f2bf(xv.w);
            *(short4v*)(x_bf + (t0+i)*DM + tid*4) = xb;
        }
        __syncthreads();
        int g = tid >> 4, n = tid & 15;
        float a0=0.f, a1=0.f, a2=0.f, a3=0.f;
        #pragma unroll 4
        for (int k = 0; k < 64; ++k) {
            float wc = Wc[(g*64 + k)*KVD + n];
            a0 += xs[0][g*64+k]*wc; a1 += xs[1][g*64+k]*wc;
            a2 += xs[2][g*64+k]*wc; a3 += xs[3][g*64+k]*wc;
        }
        part[0][g][n]=a0; part[1][g][n]=a1; part[2][g][n]=a2; part[3][g][n]=a3;
        __syncthreads();
        if (tid < 64) {
            int i = tid >> 4, nn = tid & 15;
            float s = bc[nn];
            #pragma unroll
            for (int gg = 0; gg < 16; ++gg) s += part[i][gg][nn];
            short v = f2bf(s);
            int t = t0 + i;
            kvc16[t*16 + nn] = v;
            int b = t >> 11, tl = t & (TT-1);
            kvcT[(b*32 + nn)*TT + tl]      = v;
            kvcT[(b*32 + 16 + nn)*TT + tl] = 0;   // zero pad rows 16..31
        }
    }
}

// ---------------- q' GEMM: q16 = (x @ Wq' + bq'), [BT][256] bf16 ----------------
__global__ __launch_bounds__(256) void qgemm(
    const short* __restrict__ x_bf, const short* __restrict__ Wqt,
    const float* __restrict__ bqp, short* __restrict__ q16)
{
    int bid = blockIdx.x;
    int w = threadIdx.x >> 6, lane = threadIdx.x & 63;
    int l15 = lane & 15, g = lane >> 4;
    int m0 = (bid >> 4)*64 + w*16;
    int nb = (bid & 15)*16;
    f32x4 acc = {0.f,0.f,0.f,0.f};
    const short* arow = x_bf + (m0 + l15)*DM + 8*g;
    const short* brow = Wqt  + (nb + l15)*DM + 8*g;
    for (int k0 = 0; k0 < DM; k0 += 32) {
        short8 a = *(const short8*)(arow + k0);
        short8 b = *(const short8*)(brow + k0);
        acc = __builtin_amdgcn_mfma_f32_16x16x32_bf16(a, b, acc, 0, 0, 0);
    }
    int c = nb + l15;
    float bias = bqp[c];
    #pragma unroll
    for (int r = 0; r < 4; ++r) {
        int row = m0 + 4*g + r;
        q16[row*QP + c] = f2bf(acc[r] + bias);
    }
}

// ---------------- causal latent attention, 32x32 swapped MFMA ----------------
// Block = one (b,h,32-row q-tile); 4 waves split KV range; additive combine.
// Inner loop: no LDS, no shfl; P-frag redistribution via v_permlane32_swap_b32;
// K/V tile loads software-pipelined one iteration ahead.
__global__ __launch_bounds__(256) void attn(
    const short* __restrict__ q16, const short* __restrict__ kvc16,
    const short* __restrict__ kvcT, short* __restrict__ u_bf)
{
    int bid = blockIdx.x;
    int s = bid >> 5, bh = bid & 31;
    int qt = (s & 1) ? (63 - (s >> 1)) : (s >> 1);   // causal balance pairing
    int b = bh >> 4, h = bh & 15;
    int w = threadIdx.x >> 6, lane = threadIdx.x & 63;
    int l31 = lane & 31, hi = lane >> 5;
    int qbase = qt * 32;

    __shared__ float ulds[4][32][17];
    __shared__ float dlds[4][32];

    // Q B-frag (loaded once): B[k][j]: j = l31 = q col, k = 8*hi + e (latent)
    short8 qf = *(const short8*)(q16 + (b*TT + qbase + l31)*QP + h*16 + 8*hi);
    const short* kbase = kvc16 + (b*TT + l31)*16 + 8*hi;
    const short* vrow  = kvcT + (b*32 + l31)*TT + 8*hi;

    int ntiles = qt + 1;
    int t0 = (w * ntiles) >> 2;
    int t1 = ((w + 1) * ntiles) >> 2;

    f32x16 u;
    f32x16 zf;
    #pragma unroll
    for (int r = 0; r < 16; ++r) { u[r] = 0.f; zf[r] = 0.f; }
    float lacc = 0.f;

    if (t0 < t1) {
        int kv0 = t0 << 5;
        short8 kf  = *(const short8*)(kbase + kv0*16);
        short8 va  = *(const short8*)(vrow + kv0);
        short8 vb  = *(const short8*)(vrow + kv0 + 16);
        for (int kt = t0; kt < t1; ++kt) {
            short8 kf_n = kf, va_n = va, vb_n = vb;
            if (kt + 1 < t1) {                  // prefetch next tile
                int kvn = (kt + 1) << 5;
                kf_n = *(const short8*)(kbase + kvn*16);
                va_n = *(const short8*)(vrow + kvn);
                vb_n = *(const short8*)(vrow + kvn + 16);
            }
            f32x16 st = __builtin_amdgcn_mfma_f32_32x32x16_bf16(kf, qf, zf, 0, 0, 0);
            if (kt == qt) {                      // diagonal tile: mask kv > q
                #pragma unroll
                for (int r = 0; r < 16; ++r) {
                    int kvl = (r & 3) + 8*(r >> 2) + 4*hi;
                    if (kvl > l31) st[r] = -INFINITY;
                }
            }
            float p[16];
            #pragma unroll
            for (int r = 0; r < 16; ++r) { p[r] = exp2f(st[r]); lacc += p[r]; }
            // pack pairs: wd[i] = bf16x2(p[2i],p[2i+1]); lane kv = 8j+4hi+2m, i=2j+m
            int wd[8];
            #pragma unroll
            for (int i = 0; i < 8; ++i) {
                asm("v_cvt_pk_bf16_f32 %0, %1, %2" : "=v"(wd[i]) : "v"(p[2*i]), "v"(p[2*i+1]));
            }
            // cross-half redistribute: (word0,word2) = swap(wd0,wd2); (word1,word3) = swap(wd1,wd3)
            // after swap: a' = A-word(8hi+0,1), b' = A-word(8hi+4,5) per 16-kv chunk
            int c00 = wd[0], c02 = wd[2], c01 = wd[1], c03 = wd[3];
            int c10 = wd[4], c12 = wd[6], c11 = wd[5], c13 = wd[7];
            asm volatile("v_permlane32_swap_b32 %0, %1" : "+v"(c00), "+v"(c02));
            asm volatile("v_permlane32_swap_b32 %0, %1" : "+v"(c01), "+v"(c03));
            asm volatile("v_permlane32_swap_b32 %0, %1" : "+v"(c10), "+v"(c12));
            asm volatile("v_permlane32_swap_b32 %0, %1" : "+v"(c11), "+v"(c13));
            union { int i4[4]; short8 s8; } pa0, pa1;
            pa0.i4[0]=c00; pa0.i4[1]=c01; pa0.i4[2]=c02; pa0.i4[3]=c03;
            pa1.i4[0]=c10; pa1.i4[1]=c11; pa1.i4[2]=c12; pa1.i4[3]=c13;
            u = __builtin_amdgcn_mfma_f32_32x32x16_bf16(pa0.s8, va, u, 0, 0, 0);
            u = __builtin_amdgcn_mfma_f32_32x32x16_bf16(pa1.s8, vb, u, 0, 0, 0);
            kf = kf_n; va = va_n; vb = vb_n;
        }
    }

    // combine: per-wave partials are additive (no-max softmax)
    lacc += __shfl_xor(lacc, 32, 64);
    #pragma unroll
    for (int r = 0; r < 16; ++r) {
        int q = (r & 3) + 8*(r >> 2) + 4*hi;
        if (l31 < 16) ulds[w][q][l31] = u[r];
    }
    if (hi == 0) dlds[w][l31] = lacc;
    __syncthreads();
    int tid = threadIdx.x;
    #pragma unroll
    for (int e = 0; e < 2; ++e) {
        int idx = tid*2 + e;
        int q = idx >> 4, lat = idx & 15;
        float us = ulds[0][q][lat] + ulds[1][q][lat] + ulds[2][q][lat] + ulds[3][q][lat];
        float dd = dlds[0][q] + dlds[1][q] + dlds[2][q] + dlds[3][q];
        u_bf[(b*TT + qbase + q)*QP + h*16 + lat] = f2bf(us / dd);
    }
}

// ---------------- output GEMM: out = U @ Wvo + (bo + bv@Wo) ----------------
__global__ __launch_bounds__(256) void ogemm(
    const short* __restrict__ u_bf, const short* __restrict__ Wvot,
    const float* __restrict__ bo, const float* __restrict__ bop_part,
    float* __restrict__ out)
{
    int bid = blockIdx.x;
    int w = threadIdx.x >> 6, lane = threadIdx.x & 63;
    int l15 = lane & 15, g = lane >> 4;
    int m0 = (bid >> 4)*64 + w*16;
    int nb = (bid & 15)*64;
    __shared__ float bs[64];
    int tid = threadIdx.x;
    if (tid < 64) {
        int n = nb + tid;
        float s = bo[n];
        #pragma unroll
        for (int hh = 0; hh < 16; ++hh) s += bop_part[hh*DM + n];
        bs[tid] = s;
    }
    __syncthreads();
    f32x4 acc[4];
    #pragma unroll
    for (int nt = 0; nt < 4; ++nt) acc[nt] = (f32x4){0.f,0.f,0.f,0.f};
    const short* arow = u_bf + (m0 + l15)*QP + 8*g;
    for (int k0 = 0; k0 < QP; k0 += 32) {
        short8 a = *(const short8*)(arow + k0);
        #pragma unroll
        for (int nt = 0; nt < 4; ++nt) {
            short8 bfr = *(const short8*)(Wvot + (nb + nt*16 + l15)*QP + k0 + 8*g);
            acc[nt] = __builtin_amdgcn_mfma_f32_16x16x32_bf16(a, bfr, acc[nt], 0, 0, 0);
        }
    }
    #pragma unroll
    for (int nt = 0; nt < 4; ++nt) {
        int n = nb + nt*16 + l15;
        float bias = bs[nt*16 + l15];
        #pragma unroll
        for (int r = 0; r < 4; ++r)
            out[(m0 + 4*g + r)*DM + n] = acc[nt][r] + bias;
    }
}

extern "C" void kernel_launch(void* const* d_in, const int* in_sizes, int n_in,
                              void* d_out, int out_size, void* d_ws, size_t ws_size,
                              hipStream_t stream) {
    const float* x  = (const float*)d_in[0];
    const float* Wc = (const float*)d_in[1];
    const float* bc = (const float*)d_in[2];
    const float* Wk = (const float*)d_in[3];
    // d_in[4] = bk: drops out of softmax (constant per row)
    const float* Wv = (const float*)d_in[5];
    const float* bv = (const float*)d_in[6];
    const float* Wq = (const float*)d_in[7];
    const float* bq = (const float*)d_in[8];
    const float* Wo = (const float*)d_in[9];
    const float* bo = (const float*)d_in[10];
    // d_in[11] = mask: causal, implemented directly
    float* out = (float*)d_out;

    char* ws = (char*)d_ws;                       // needs 16 MiB
    short* x_bf     = (short*)(ws);                              // 8 MiB
    short* Wqt      = (short*)(ws + (8u<<20));                   // 512 KiB
    short* Wvot     = (short*)(ws + (8u<<20) + (512u<<10));      // 512 KiB
    float* bqp      = (float*)(ws + (9u<<20));                   // 1 KiB
    float* bop_part = (float*)(ws + (9u<<20) + 8192);            // 64 KiB
    short* kvc16    = (short*)(ws + (9u<<20) + (512u<<10));      // 128 KiB
    short* kvcT     = (short*)(ws + (9u<<20) + (768u<<10));      // 256 KiB [B][32][T]
    short* q16      = (short*)(ws + (10u<<20));                  // 2 MiB [BT][256]
    short* u_bf     = (short*)(ws + (14u<<20));                  // 2 MiB

    hipLaunchKernelGGL(prep_all, dim3(1344), dim3(256), 0, stream,
                       Wq, Wk, bq, Wv, Wo, bv, x, Wc, bc,
                       Wqt, bqp, Wvot, bop_part, x_bf, kvc16, kvcT);
    hipLaunchKernelGGL(qgemm,    dim3(1024), dim3(256), 0, stream,
                       x_bf, Wqt, bqp, q16);
    hipLaunchKernelGGL(attn,     dim3(2048), dim3(256), 0, stream,
                       q16, kvc16, kvcT, u_bf);
    hipLaunchKernelGGL(ogemm,    dim3(1024), dim3(256), 0, stream,
                       u_bf, Wvot, bo, bop_part, out);
}